// Round 10
// baseline (59.038 us; speedup 1.0000x reference)
//
#include <hip/hip_runtime.h>

#define T_FRAMES 256
#define D_IN 80
#define CCH 256
#define CCEP 222
#define FFT_N 1024
#define HOP 256
#define WINL 512
#define PF_KT 128
#define ZLEN 65536

__device__ __forceinline__ unsigned br10(unsigned x) { return __brev(x) >> 22; }

// ---- K1: conv1. 128 blocks x 512 thr; thread-half f owns frame 2b+f.
//      inputs: LDS b128 broadcast; weights: per-thread float4 row reads (original OIW layout) ----
__global__ __launch_bounds__(512) void conv1_k(const float* __restrict__ x, const float* __restrict__ w1,
                                               const float* __restrict__ b1, float* __restrict__ h1) {
  __shared__ float4 xs4[4 * 20];  // frames 2b-1 .. 2b+2
  const int b = blockIdx.x, tid = threadIdx.x;
  const float4* x4 = (const float4*)x;
  if (tid < 80) {
    int r = tid / 20, cg = tid - r * 20;
    int tt = 2 * b - 1 + r;
    xs4[tid] = (tt >= 0 && tt < T_FRAMES) ? x4[tt * 20 + cg] : make_float4(0.f, 0.f, 0.f, 0.f);
  }
  __syncthreads();
  const int f = tid >> 8, c = tid & 255;
  const int t = 2 * b + f;
  const float4* wr = (const float4*)(w1 + c * 240);  // 60 float4, contiguous per thread
  float acc = b1[c];
  #pragma unroll 5
  for (int cg = 0; cg < 20; ++cg) {
    float4 w0 = wr[cg * 3 + 0], w1v = wr[cg * 3 + 1], w2v = wr[cg * 3 + 2];
    float4 xr0 = xs4[(f + 0) * 20 + cg];
    float4 xr1 = xs4[(f + 1) * 20 + cg];
    float4 xr2 = xs4[(f + 2) * 20 + cg];
    acc += xr0.x * w0.x  + xr1.x * w0.y  + xr2.x * w0.z;
    acc += xr0.y * w0.w  + xr1.y * w1v.x + xr2.y * w1v.y;
    acc += xr0.z * w1v.z + xr1.z * w1v.w + xr2.z * w2v.x;
    acc += xr0.w * w2v.y + xr1.w * w2v.z + xr2.w * w2v.w;
  }
  h1[t * CCH + c] = fmaxf(acc, 0.f);
}

// ---- K2: conv2 split-K x4 partials. 256 blocks x 512 thr; halves own frame-pairs.
//      weights: per-thread float4 reads of w2 row slice (192 floats) ----
__global__ __launch_bounds__(512) void conv2_k(const float* __restrict__ h1, const float* __restrict__ w2,
                                               float* __restrict__ h2p) {
  __shared__ float4 hs4[6 * 16];  // frames t0-1 .. t0+4, cin chunk of 64
  const int b = blockIdx.x, tid = threadIdx.x;
  const int g = b >> 2, kc = b & 3, t0 = g << 2;
  const float4* h14 = (const float4*)h1;  // [t][64]
  if (tid < 96) {
    int r = tid >> 4, cg = tid & 15;
    int tt = t0 - 1 + r;
    hs4[tid] = (tt >= 0 && tt < T_FRAMES) ? h14[tt * 64 + (kc << 4) + cg] : make_float4(0.f, 0.f, 0.f, 0.f);
  }
  __syncthreads();
  const int fb = (tid >> 8) << 1, c = tid & 255;
  const float4* wr = (const float4*)(w2 + c * 768 + (kc << 6) * 3);  // 48 float4, contiguous
  float a0 = 0.f, a1 = 0.f;
  #pragma unroll 4
  for (int cg = 0; cg < 16; ++cg) {
    float4 w0 = wr[cg * 3 + 0], w1v = wr[cg * 3 + 1], w2v = wr[cg * 3 + 2];
    float4 hr0 = hs4[(fb + 0) * 16 + cg];
    float4 hr1 = hs4[(fb + 1) * 16 + cg];
    float4 hr2 = hs4[(fb + 2) * 16 + cg];
    float4 hr3 = hs4[(fb + 3) * 16 + cg];
    a0 += hr0.x * w0.x  + hr1.x * w0.y  + hr2.x * w0.z;
    a0 += hr0.y * w0.w  + hr1.y * w1v.x + hr2.y * w1v.y;
    a0 += hr0.z * w1v.z + hr1.z * w1v.w + hr2.z * w2v.x;
    a0 += hr0.w * w2v.y + hr1.w * w2v.z + hr2.w * w2v.w;
    a1 += hr1.x * w0.x  + hr2.x * w0.y  + hr3.x * w0.z;
    a1 += hr1.y * w0.w  + hr2.y * w1v.x + hr3.y * w1v.y;
    a1 += hr1.z * w1v.z + hr2.z * w1v.w + hr3.z * w2v.x;
    a1 += hr1.w * w2v.y + hr2.w * w2v.z + hr3.w * w2v.w;
  }
  const int ob = kc << 8;
  h2p[(ob + t0 + fb + 0) * CCH + c] = a0;
  h2p[(ob + t0 + fb + 1) * CCH + c] = a1;
}

// ---- K3: conv3 split-K x4 (sums conv2 partials + bias2 + relu in staging);
//      weights: per-thread float4 reads of w3 row slice ----
__global__ __launch_bounds__(512) void conv3_k(const float* __restrict__ h2p, const float* __restrict__ w3,
                                               const float* __restrict__ b2, float* __restrict__ ccp) {
  __shared__ float4 hs4[6 * 16];
  const int b = blockIdx.x, tid = threadIdx.x;
  const int g = b >> 2, kc = b & 3, t0 = g << 2;
  const float4* h2p4 = (const float4*)h2p;
  const float4* b24 = (const float4*)b2;
  if (tid < 96) {
    int r = tid >> 4, cg = tid & 15;
    int tt = t0 - 1 + r;
    float4 s = make_float4(0.f, 0.f, 0.f, 0.f);
    if (tt >= 0 && tt < T_FRAMES) {
      s = b24[(kc << 4) + cg];
      #pragma unroll
      for (int p = 0; p < 4; ++p) {
        float4 v = h2p4[((p << 8) + tt) * 64 + (kc << 4) + cg];
        s.x += v.x; s.y += v.y; s.z += v.z; s.w += v.w;
      }
      s.x = fmaxf(s.x, 0.f); s.y = fmaxf(s.y, 0.f); s.z = fmaxf(s.z, 0.f); s.w = fmaxf(s.w, 0.f);
    }
    hs4[tid] = s;
  }
  __syncthreads();
  const int fb = (tid >> 8) << 1, c = tid & 255;
  if (c < CCEP) {
    const float4* wr = (const float4*)(w3 + c * 768 + (kc << 6) * 3);
    float a0 = 0.f, a1 = 0.f;
    #pragma unroll 4
    for (int cg = 0; cg < 16; ++cg) {
      float4 w0 = wr[cg * 3 + 0], w1v = wr[cg * 3 + 1], w2v = wr[cg * 3 + 2];
      float4 hr0 = hs4[(fb + 0) * 16 + cg];
      float4 hr1 = hs4[(fb + 1) * 16 + cg];
      float4 hr2 = hs4[(fb + 2) * 16 + cg];
      float4 hr3 = hs4[(fb + 3) * 16 + cg];
      a0 += hr0.x * w0.x  + hr1.x * w0.y  + hr2.x * w0.z;
      a0 += hr0.y * w0.w  + hr1.y * w1v.x + hr2.y * w1v.y;
      a0 += hr0.z * w1v.z + hr1.z * w1v.w + hr2.z * w2v.x;
      a0 += hr0.w * w2v.y + hr1.w * w2v.z + hr2.w * w2v.w;
      a1 += hr1.x * w0.x  + hr2.x * w0.y  + hr3.x * w0.z;
      a1 += hr1.y * w0.w  + hr2.y * w1v.x + hr3.y * w1v.y;
      a1 += hr1.z * w1v.z + hr2.z * w1v.w + hr3.z * w2v.x;
      a1 += hr1.w * w2v.y + hr2.w * w2v.z + hr3.w * w2v.w;
    }
    const int ob = kc << 8;
    ccp[(ob + t0 + fb + 0) * CCEP + c] = a0;
    ccp[(ob + t0 + fb + 1) * CCEP + c] = a1;
  }
}

// ---- K4: fused spectral kernel (correlation theorem, one fwd + one inv FFT) ----
__global__ __launch_bounds__(512) void fftltv_k(const float* __restrict__ ccp, const float* __restrict__ b3,
                                                const float* __restrict__ quef, const float* __restrict__ z,
                                                const float* __restrict__ win, float* __restrict__ outw) {
  __shared__ float2 U[FFT_N];
  int t = blockIdx.x, tid = threadIdx.x;
  for (int i = tid; i < FFT_N; i += 512) {
    unsigned q = br10((unsigned)i);
    float a = 0.f, bv = 0.f;
    if (q >= 401u && q < 623u) {
      int cq = (int)(q - 401u);
      int base = t * CCEP + cq;
      a = (b3[cq] + ccp[base] + ccp[256 * CCEP + base] + ccp[512 * CCEP + base] + ccp[768 * CCEP + base]) / quef[cq];
    }
    if (q < 512u) {
      int idx = t * HOP + (int)q - 255;
      bv = (idx >= 0 && idx < ZLEN) ? z[idx] : 0.f;
    }
    U[i] = make_float2(a, bv);
  }
  __syncthreads();
  #pragma unroll
  for (int s = 1; s <= 10; ++s) {
    int half = 1 << (s - 1);
    int pos = tid & (half - 1);
    int i1 = ((tid >> (s - 1)) << s) + pos;
    int i2 = i1 + half;
    float ang = (-6.283185307179586f / (float)(1 << s)) * (float)pos;
    float sn, cs; __sincosf(ang, &sn, &cs);
    float2 v2 = U[i2], v1 = U[i1];
    float tr = cs * v2.x - sn * v2.y;
    float ti = cs * v2.y + sn * v2.x;
    U[i1] = make_float2(v1.x + tr, v1.y + ti);
    U[i2] = make_float2(v1.x - tr, v1.y - ti);
    __syncthreads();
  }
  {
    int j = tid;
    int mj = (FFT_N - j) & (FFT_N - 1);
    float2 Uj = U[j], Um = U[mj];
    float2 U5j = make_float2(0.f, 0.f);
    if (tid == 0) U5j = U[512];
    auto pcalc = [](float2 Uj, float2 Um) -> float2 {
      float Ar = 0.5f * (Uj.x + Um.x);
      float Ai = 0.5f * (Uj.y - Um.y);
      float Bx = 0.5f * (Uj.y + Um.y);
      float By = 0.5f * (Um.x - Uj.x);
      float mag = __expf(0.23025850929940457f * Ar);
      float sn, cs; __sincosf(Ai, &sn, &cs);
      float SPx = mag * cs, SPy = mag * sn;
      return make_float2(Bx * SPx + By * SPy, Bx * SPy - By * SPx);
    };
    float2 Pj = pcalc(Uj, Um);
    float2 P5 = (tid == 0) ? pcalc(U5j, U5j) : make_float2(0.f, 0.f);
    __syncthreads();
    U[j] = Pj;
    if (tid == 0) U[512] = P5;
    else U[mj] = make_float2(Pj.x, -Pj.y);
  }
  __syncthreads();
  #pragma unroll
  for (int s = 10; s >= 1; --s) {
    int half = 1 << (s - 1);
    int pos = tid & (half - 1);
    int i1 = ((tid >> (s - 1)) << s) + pos;
    int i2 = i1 + half;
    float ang = (6.283185307179586f / (float)(1 << s)) * (float)pos;
    float sn, cs; __sincosf(ang, &sn, &cs);
    float2 v1 = U[i1], v2 = U[i2];
    U[i1] = make_float2(v1.x + v2.x, v1.y + v2.y);
    float dr = v1.x - v2.x, di = v1.y - v2.y;
    U[i2] = make_float2(cs * dr - sn * di, cs * di + sn * dr);
    __syncthreads();
  }
  const float inv = 1.0f / (float)FFT_N;
  for (int i = tid; i < FFT_N; i += 512) {
    unsigned m = br10((unsigned)i);
    if (m < 512u) {
      int w = 511 - (int)m;
      outw[t * WINL + w] = U[i].x * inv * win[w];
    }
  }
}

// ---- K5: overlap-add (circular roll over t) + 128-tap postfilter ----
__global__ __launch_bounds__(256) void pf_k(const float* __restrict__ outw, const float* __restrict__ pf_w,
                                            const float* __restrict__ pf_b, float* __restrict__ y) {
  __shared__ float sb[256 + PF_KT - 1];
  __shared__ float wpf[PF_KT];
  int n0 = blockIdx.x * 256;
  for (int i = threadIdx.x; i < 256 + PF_KT - 1; i += 256) {
    int m = n0 - 63 + i;
    float v = 0.f;
    if (m >= 0 && m < ZLEN) {
      int t = m >> 8, j = m & 255;
      v = outw[t * WINL + j] + outw[((t - 1) & 255) * WINL + HOP + j];
    }
    sb[i] = v;
  }
  if (threadIdx.x < PF_KT) wpf[threadIdx.x] = pf_w[threadIdx.x];
  __syncthreads();
  float acc = pf_b[0];
  #pragma unroll 8
  for (int j = 0; j < PF_KT; ++j) acc += sb[threadIdx.x + j] * wpf[j];
  y[n0 + threadIdx.x] = acc;
}

extern "C" void kernel_launch(void* const* d_in, const int* in_sizes, int n_in,
                              void* d_out, int out_size, void* d_ws, size_t ws_size,
                              hipStream_t stream) {
  const float* x    = (const float*)d_in[0];
  const float* z    = (const float*)d_in[1];
  const float* w1   = (const float*)d_in[2];
  const float* b1   = (const float*)d_in[3];
  const float* w2   = (const float*)d_in[4];
  const float* b2   = (const float*)d_in[5];
  const float* w3   = (const float*)d_in[6];
  const float* b3   = (const float*)d_in[7];
  const float* pf_w = (const float*)d_in[8];
  const float* pf_b = (const float*)d_in[9];
  const float* quef = (const float*)d_in[10];
  const float* win  = (const float*)d_in[11];
  float* out = (float*)d_out;
  float* ws  = (float*)d_ws;

  // workspace layout (floats)
  float* h1   = ws;                 // 256*256   = 65536
  float* h2p  = h1 + 65536;         // 4*256*256 = 262144
  float* ccp  = h2p + 262144;       // 4*256*222 = 227328
  float* outw = ccp + 227328;       // 256*512   = 131072

  conv1_k<<<128, 512, 0, stream>>>(x, w1, b1, h1);
  conv2_k<<<256, 512, 0, stream>>>(h1, w2, h2p);
  conv3_k<<<256, 512, 0, stream>>>(h2p, w3, b2, ccp);
  fftltv_k<<<T_FRAMES, 512, 0, stream>>>(ccp, b3, quef, z, win, outw);
  pf_k<<<ZLEN / 256, 256, 0, stream>>>(outw, pf_w, pf_b, out);
}

// Round 12
// 43.646 us; speedup vs baseline: 1.3526x; 1.3526x over previous
//
#include <hip/hip_runtime.h>

#define T_FRAMES 256
#define D_IN 80
#define CCH 256
#define CCEP 222
#define FFT_N 1024
#define HOP 256
#define WINL 512
#define PF_KT 128
#define ZLEN 65536

__device__ __forceinline__ unsigned br10(unsigned x) { return __brev(x) >> 22; }

// =============== shared conv inner loop ===============
// wlds4[j4*256+c]: 12 f4 per c (16 cin x 3 taps). inlds4[row*4+cg]: 18 rows x 4 f4 (16 cin).
// Thread (c, fh): 8 frames fh*8+j. Per cg: 3 weight b128 (coalesced) + 10 input b128 (broadcast), 96 FMA.
__device__ __forceinline__ void conv_inner(const float4* __restrict__ wlds4,
                                           const float4* __restrict__ inlds4,
                                           int c, int fh, float* __restrict__ acc) {
  #pragma unroll
  for (int cg = 0; cg < 4; ++cg) {
    float4 w0 = wlds4[(cg * 3 + 0) * 256 + c];
    float4 w1v = wlds4[(cg * 3 + 1) * 256 + c];
    float4 w2v = wlds4[(cg * 3 + 2) * 256 + c];
    float4 xr[10];
    #pragma unroll
    for (int r = 0; r < 10; ++r) xr[r] = inlds4[(fh * 8 + r) * 4 + cg];
    #pragma unroll
    for (int j = 0; j < 8; ++j) {
      float4 xa = xr[j], xb = xr[j + 1], xc = xr[j + 2];
      acc[j] += xa.x * w0.x  + xb.x * w0.y  + xc.x * w0.z
              + xa.y * w0.w  + xb.y * w1v.x + xc.y * w1v.y
              + xa.z * w1v.z + xb.z * w1v.w + xc.z * w2v.x
              + xa.w * w2v.y + xb.w * w2v.z + xc.w * w2v.w;
    }
  }
}

// ---- K1: conv1 partials. grid (5 kc, 16 g). out h1p[kc][t][c] ----
__global__ __launch_bounds__(512) void conv1_k(const float* __restrict__ x, const float* __restrict__ w1,
                                               float* __restrict__ h1p) {
  __shared__ float4 wlds4[12 * 256];  // 48 KB
  __shared__ float4 inlds4[18 * 4];
  const int kc = blockIdx.x, g = blockIdx.y, tid = threadIdx.x;
  const int t0 = g << 4;
  const float4* w14 = (const float4*)w1;  // row = 60 f4
  const float4* x4 = (const float4*)x;    // row = 20 f4
  #pragma unroll
  for (int it = 0; it < 6; ++it) {
    int idx = it * 512 + tid, cc = idx & 255, j4 = idx >> 8;
    wlds4[j4 * 256 + cc] = w14[cc * 60 + kc * 12 + j4];
  }
  if (tid < 72) {
    int r = tid >> 2, cg = tid & 3, tt = t0 - 1 + r;
    inlds4[tid] = (tt >= 0 && tt < T_FRAMES) ? x4[tt * 20 + kc * 4 + cg] : make_float4(0.f, 0.f, 0.f, 0.f);
  }
  __syncthreads();
  const int c = tid & 255, fh = tid >> 8;
  float acc[8] = {0.f, 0.f, 0.f, 0.f, 0.f, 0.f, 0.f, 0.f};
  conv_inner(wlds4, inlds4, c, fh, acc);
  const int ob = kc << 8;
  #pragma unroll
  for (int j = 0; j < 8; ++j) h1p[(ob + t0 + fh * 8 + j) * CCH + c] = acc[j];
}

// ---- K2: conv2 partials. grid (16 kc, 16 g). input h1 = relu(b1 + sum5 h1p) ----
__global__ __launch_bounds__(512) void conv2_k(const float* __restrict__ h1p, const float* __restrict__ b1,
                                               const float* __restrict__ w2, float* __restrict__ h2p) {
  __shared__ float4 wlds4[12 * 256];
  __shared__ float4 inlds4[18 * 4];
  const int kc = blockIdx.x, g = blockIdx.y, tid = threadIdx.x;
  const int t0 = g << 4;
  const float4* w24 = (const float4*)w2;    // row = 192 f4
  const float4* h1p4 = (const float4*)h1p;  // row = 64 f4
  const float4* b14 = (const float4*)b1;
  #pragma unroll
  for (int it = 0; it < 6; ++it) {
    int idx = it * 512 + tid, cc = idx & 255, j4 = idx >> 8;
    wlds4[j4 * 256 + cc] = w24[cc * 192 + kc * 12 + j4];
  }
  if (tid < 72) {
    int r = tid >> 2, cg = tid & 3, tt = t0 - 1 + r;
    float4 s = make_float4(0.f, 0.f, 0.f, 0.f);
    if (tt >= 0 && tt < T_FRAMES) {
      s = b14[kc * 4 + cg];
      #pragma unroll
      for (int p = 0; p < 5; ++p) {
        float4 v = h1p4[((p << 8) + tt) * 64 + kc * 4 + cg];
        s.x += v.x; s.y += v.y; s.z += v.z; s.w += v.w;
      }
      s.x = fmaxf(s.x, 0.f); s.y = fmaxf(s.y, 0.f); s.z = fmaxf(s.z, 0.f); s.w = fmaxf(s.w, 0.f);
    }
    inlds4[tid] = s;
  }
  __syncthreads();
  const int c = tid & 255, fh = tid >> 8;
  float acc[8] = {0.f, 0.f, 0.f, 0.f, 0.f, 0.f, 0.f, 0.f};
  conv_inner(wlds4, inlds4, c, fh, acc);
  const int ob = kc << 8;
  #pragma unroll
  for (int j = 0; j < 8; ++j) h2p[(ob + t0 + fh * 8 + j) * CCH + c] = acc[j];
}

// ---- K3: conv3 partials. grid (16 kc, 16 g). input h2 = relu(b2 + sum16 h2p); out ccp[kc][t][222] ----
__global__ __launch_bounds__(512) void conv3_k(const float* __restrict__ h2p, const float* __restrict__ b2,
                                               const float* __restrict__ w3, float* __restrict__ ccp) {
  __shared__ float4 wlds4[12 * 256];
  __shared__ float4 inlds4[18 * 4];
  const int kc = blockIdx.x, g = blockIdx.y, tid = threadIdx.x;
  const int t0 = g << 4;
  const float4* w34 = (const float4*)w3;    // row = 192 f4
  const float4* h2p4 = (const float4*)h2p;  // row = 64 f4
  const float4* b24 = (const float4*)b2;
  #pragma unroll
  for (int it = 0; it < 6; ++it) {
    int idx = it * 512 + tid, cc = idx & 255, j4 = idx >> 8;
    if (cc < CCEP) wlds4[j4 * 256 + cc] = w34[cc * 192 + kc * 12 + j4];
  }
  if (tid < 72) {
    int r = tid >> 2, cg = tid & 3, tt = t0 - 1 + r;
    float4 s = make_float4(0.f, 0.f, 0.f, 0.f);
    if (tt >= 0 && tt < T_FRAMES) {
      s = b24[kc * 4 + cg];
      #pragma unroll
      for (int p = 0; p < 16; ++p) {
        float4 v = h2p4[((p << 8) + tt) * 64 + kc * 4 + cg];
        s.x += v.x; s.y += v.y; s.z += v.z; s.w += v.w;
      }
      s.x = fmaxf(s.x, 0.f); s.y = fmaxf(s.y, 0.f); s.z = fmaxf(s.z, 0.f); s.w = fmaxf(s.w, 0.f);
    }
    inlds4[tid] = s;
  }
  __syncthreads();
  const int c = tid & 255, fh = tid >> 8;
  if (c < CCEP) {
    float acc[8] = {0.f, 0.f, 0.f, 0.f, 0.f, 0.f, 0.f, 0.f};
    conv_inner(wlds4, inlds4, c, fh, acc);
    const int ob = kc << 8;
    #pragma unroll
    for (int j = 0; j < 8; ++j) ccp[(ob + t0 + fh * 8 + j) * CCEP + c] = acc[j];
  }
}

// ---- K4: fused spectral kernel (correlation theorem, one fwd + one inv FFT) ----
__global__ __launch_bounds__(512) void fftltv_k(const float* __restrict__ ccp, const float* __restrict__ b3,
                                                const float* __restrict__ quef, const float* __restrict__ z,
                                                const float* __restrict__ win, float* __restrict__ outw) {
  __shared__ float2 U[FFT_N];
  int t = blockIdx.x, tid = threadIdx.x;
  for (int i = tid; i < FFT_N; i += 512) {
    unsigned q = br10((unsigned)i);
    float a = 0.f, bv = 0.f;
    if (q >= 401u && q < 623u) {
      int cq = (int)(q - 401u);
      float s = b3[cq];
      #pragma unroll
      for (int p = 0; p < 16; ++p) s += ccp[((p << 8) + t) * CCEP + cq];
      a = s / quef[cq];
    }
    if (q < 512u) {
      int idx = t * HOP + (int)q - 255;
      bv = (idx >= 0 && idx < ZLEN) ? z[idx] : 0.f;
    }
    U[i] = make_float2(a, bv);
  }
  __syncthreads();
  #pragma unroll
  for (int s = 1; s <= 10; ++s) {
    int half = 1 << (s - 1);
    int pos = tid & (half - 1);
    int i1 = ((tid >> (s - 1)) << s) + pos;
    int i2 = i1 + half;
    float ang = (-6.283185307179586f / (float)(1 << s)) * (float)pos;
    float sn, cs; __sincosf(ang, &sn, &cs);
    float2 v2 = U[i2], v1 = U[i1];
    float tr = cs * v2.x - sn * v2.y;
    float ti = cs * v2.y + sn * v2.x;
    U[i1] = make_float2(v1.x + tr, v1.y + ti);
    U[i2] = make_float2(v1.x - tr, v1.y - ti);
    __syncthreads();
  }
  {
    int j = tid;
    int mj = (FFT_N - j) & (FFT_N - 1);
    float2 Uj = U[j], Um = U[mj];
    float2 U5j = make_float2(0.f, 0.f);
    if (tid == 0) U5j = U[512];
    auto pcalc = [](float2 Uj, float2 Um) -> float2 {
      float Ar = 0.5f * (Uj.x + Um.x);
      float Ai = 0.5f * (Uj.y - Um.y);
      float Bx = 0.5f * (Uj.y + Um.y);
      float By = 0.5f * (Um.x - Uj.x);
      float mag = __expf(0.23025850929940457f * Ar);
      float sn, cs; __sincosf(Ai, &sn, &cs);
      float SPx = mag * cs, SPy = mag * sn;
      return make_float2(Bx * SPx + By * SPy, Bx * SPy - By * SPx);
    };
    float2 Pj = pcalc(Uj, Um);
    float2 P5 = (tid == 0) ? pcalc(U5j, U5j) : make_float2(0.f, 0.f);
    __syncthreads();
    U[j] = Pj;
    if (tid == 0) U[512] = P5;
    else U[mj] = make_float2(Pj.x, -Pj.y);
  }
  __syncthreads();
  #pragma unroll
  for (int s = 10; s >= 1; --s) {
    int half = 1 << (s - 1);
    int pos = tid & (half - 1);
    int i1 = ((tid >> (s - 1)) << s) + pos;
    int i2 = i1 + half;
    float ang = (6.283185307179586f / (float)(1 << s)) * (float)pos;
    float sn, cs; __sincosf(ang, &sn, &cs);
    float2 v1 = U[i1], v2 = U[i2];
    U[i1] = make_float2(v1.x + v2.x, v1.y + v2.y);
    float dr = v1.x - v2.x, di = v1.y - v2.y;
    U[i2] = make_float2(cs * dr - sn * di, cs * di + sn * dr);
    __syncthreads();
  }
  const float inv = 1.0f / (float)FFT_N;
  for (int i = tid; i < FFT_N; i += 512) {
    unsigned m = br10((unsigned)i);
    if (m < 512u) {
      int w = 511 - (int)m;
      outw[t * WINL + w] = U[i].x * inv * win[w];
    }
  }
}

// ---- K5: overlap-add (circular roll over t) + 128-tap postfilter ----
__global__ __launch_bounds__(256) void pf_k(const float* __restrict__ outw, const float* __restrict__ pf_w,
                                            const float* __restrict__ pf_b, float* __restrict__ y) {
  __shared__ float sb[256 + PF_KT - 1];
  __shared__ float wpf[PF_KT];
  int n0 = blockIdx.x * 256;
  for (int i = threadIdx.x; i < 256 + PF_KT - 1; i += 256) {
    int m = n0 - 63 + i;
    float v = 0.f;
    if (m >= 0 && m < ZLEN) {
      int t = m >> 8, j = m & 255;
      v = outw[t * WINL + j] + outw[((t - 1) & 255) * WINL + HOP + j];
    }
    sb[i] = v;
  }
  if (threadIdx.x < PF_KT) wpf[threadIdx.x] = pf_w[threadIdx.x];
  __syncthreads();
  float acc = pf_b[0];
  #pragma unroll 8
  for (int j = 0; j < PF_KT; ++j) acc += sb[threadIdx.x + j] * wpf[j];
  y[n0 + threadIdx.x] = acc;
}

extern "C" void kernel_launch(void* const* d_in, const int* in_sizes, int n_in,
                              void* d_out, int out_size, void* d_ws, size_t ws_size,
                              hipStream_t stream) {
  const float* x    = (const float*)d_in[0];
  const float* z    = (const float*)d_in[1];
  const float* w1   = (const float*)d_in[2];
  const float* b1   = (const float*)d_in[3];
  const float* w2   = (const float*)d_in[4];
  const float* b2   = (const float*)d_in[5];
  const float* w3   = (const float*)d_in[6];
  const float* b3   = (const float*)d_in[7];
  const float* pf_w = (const float*)d_in[8];
  const float* pf_b = (const float*)d_in[9];
  const float* quef = (const float*)d_in[10];
  const float* win  = (const float*)d_in[11];
  float* out = (float*)d_out;
  float* ws  = (float*)d_ws;

  // workspace layout (floats)
  float* h1p  = ws;                 // 5*256*256  = 327680
  float* h2p  = h1p + 327680;       // 16*256*256 = 1048576
  float* ccp  = h2p + 1048576;      // 16*256*222 = 909312
  float* outw = ccp + 909312;       // 256*512    = 131072

  conv1_k<<<dim3(5, 16), 512, 0, stream>>>(x, w1, h1p);
  // conv2 launched 3x intentionally (idempotent) to expose its exact duration via next-round delta
  conv2_k<<<dim3(16, 16), 512, 0, stream>>>(h1p, b1, w2, h2p);
  conv2_k<<<dim3(16, 16), 512, 0, stream>>>(h1p, b1, w2, h2p);
  conv2_k<<<dim3(16, 16), 512, 0, stream>>>(h1p, b1, w2, h2p);
  conv3_k<<<dim3(16, 16), 512, 0, stream>>>(h2p, b2, w3, ccp);
  fftltv_k<<<T_FRAMES, 512, 0, stream>>>(ccp, b3, quef, z, win, outw);
  pf_k<<<ZLEN / 256, 256, 0, stream>>>(outw, pf_w, pf_b, out);
}

// Round 13
// 33.620 us; speedup vs baseline: 1.7561x; 1.2982x over previous
//
#include <hip/hip_runtime.h>

#define T_FRAMES 256
#define D_IN 80
#define CCH 256
#define CCEP 222
#define FFT_N 1024
#define HOP 256
#define WINL 512
#define PF_KT 128
#define ZLEN 65536

__device__ __forceinline__ unsigned br10(unsigned x) { return __brev(x) >> 22; }

// =============== shared conv inner loop ===============
// wlds4[j4*256+c]: 12 f4 per c (16 cin x 3 taps). inlds4[row*4+cg]: 18 rows x 4 f4 (16 cin).
// Thread (c, fh): 8 frames fh*8+j. Per cg: 3 weight b128 (coalesced) + 10 input b128 (broadcast), 96 FMA.
__device__ __forceinline__ void conv_inner(const float4* __restrict__ wlds4,
                                           const float4* __restrict__ inlds4,
                                           int c, int fh, float* __restrict__ acc) {
  #pragma unroll
  for (int cg = 0; cg < 4; ++cg) {
    float4 w0 = wlds4[(cg * 3 + 0) * 256 + c];
    float4 w1v = wlds4[(cg * 3 + 1) * 256 + c];
    float4 w2v = wlds4[(cg * 3 + 2) * 256 + c];
    float4 xr[10];
    #pragma unroll
    for (int r = 0; r < 10; ++r) xr[r] = inlds4[(fh * 8 + r) * 4 + cg];
    #pragma unroll
    for (int j = 0; j < 8; ++j) {
      float4 xa = xr[j], xb = xr[j + 1], xc = xr[j + 2];
      acc[j] += xa.x * w0.x  + xb.x * w0.y  + xc.x * w0.z
              + xa.y * w0.w  + xb.y * w1v.x + xc.y * w1v.y
              + xa.z * w1v.z + xb.z * w1v.w + xc.z * w2v.x
              + xa.w * w2v.y + xb.w * w2v.z + xc.w * w2v.w;
    }
  }
}

// ---- K1: conv1 partials. grid (5 kc, 16 g). out h1p[kc][t][c] ----
__global__ __launch_bounds__(512) void conv1_k(const float* __restrict__ x, const float* __restrict__ w1,
                                               float* __restrict__ h1p) {
  __shared__ float4 wlds4[12 * 256];  // 48 KB
  __shared__ float4 inlds4[18 * 4];
  const int kc = blockIdx.x, g = blockIdx.y, tid = threadIdx.x;
  const int t0 = g << 4;
  const float4* w14 = (const float4*)w1;  // row = 60 f4
  const float4* x4 = (const float4*)x;    // row = 20 f4
  #pragma unroll
  for (int it = 0; it < 6; ++it) {
    int idx = it * 512 + tid, cc = idx & 255, j4 = idx >> 8;
    wlds4[j4 * 256 + cc] = w14[cc * 60 + kc * 12 + j4];
  }
  if (tid < 72) {
    int r = tid >> 2, cg = tid & 3, tt = t0 - 1 + r;
    inlds4[tid] = (tt >= 0 && tt < T_FRAMES) ? x4[tt * 20 + kc * 4 + cg] : make_float4(0.f, 0.f, 0.f, 0.f);
  }
  __syncthreads();
  const int c = tid & 255, fh = tid >> 8;
  float acc[8] = {0.f, 0.f, 0.f, 0.f, 0.f, 0.f, 0.f, 0.f};
  conv_inner(wlds4, inlds4, c, fh, acc);
  const int ob = kc << 8;
  #pragma unroll
  for (int j = 0; j < 8; ++j) h1p[(ob + t0 + fh * 8 + j) * CCH + c] = acc[j];
}

// ---- K2: conv2 partials. grid (16 kc, 16 g). input h1 = relu(b1 + sum5 h1p) ----
__global__ __launch_bounds__(512) void conv2_k(const float* __restrict__ h1p, const float* __restrict__ b1,
                                               const float* __restrict__ w2, float* __restrict__ h2p) {
  __shared__ float4 wlds4[12 * 256];
  __shared__ float4 inlds4[18 * 4];
  const int kc = blockIdx.x, g = blockIdx.y, tid = threadIdx.x;
  const int t0 = g << 4;
  const float4* w24 = (const float4*)w2;    // row = 192 f4
  const float4* h1p4 = (const float4*)h1p;  // row = 64 f4
  const float4* b14 = (const float4*)b1;
  #pragma unroll
  for (int it = 0; it < 6; ++it) {
    int idx = it * 512 + tid, cc = idx & 255, j4 = idx >> 8;
    wlds4[j4 * 256 + cc] = w24[cc * 192 + kc * 12 + j4];
  }
  if (tid < 72) {
    int r = tid >> 2, cg = tid & 3, tt = t0 - 1 + r;
    float4 s = make_float4(0.f, 0.f, 0.f, 0.f);
    if (tt >= 0 && tt < T_FRAMES) {
      s = b14[kc * 4 + cg];
      #pragma unroll
      for (int p = 0; p < 5; ++p) {
        float4 v = h1p4[((p << 8) + tt) * 64 + kc * 4 + cg];
        s.x += v.x; s.y += v.y; s.z += v.z; s.w += v.w;
      }
      s.x = fmaxf(s.x, 0.f); s.y = fmaxf(s.y, 0.f); s.z = fmaxf(s.z, 0.f); s.w = fmaxf(s.w, 0.f);
    }
    inlds4[tid] = s;
  }
  __syncthreads();
  const int c = tid & 255, fh = tid >> 8;
  float acc[8] = {0.f, 0.f, 0.f, 0.f, 0.f, 0.f, 0.f, 0.f};
  conv_inner(wlds4, inlds4, c, fh, acc);
  const int ob = kc << 8;
  #pragma unroll
  for (int j = 0; j < 8; ++j) h2p[(ob + t0 + fh * 8 + j) * CCH + c] = acc[j];
}

// ---- K3: conv3 partials. grid (16 kc, 16 g). input h2 = relu(b2 + sum16 h2p); out ccp[kc][t][222] ----
__global__ __launch_bounds__(512) void conv3_k(const float* __restrict__ h2p, const float* __restrict__ b2,
                                               const float* __restrict__ w3, float* __restrict__ ccp) {
  __shared__ float4 wlds4[12 * 256];
  __shared__ float4 inlds4[18 * 4];
  const int kc = blockIdx.x, g = blockIdx.y, tid = threadIdx.x;
  const int t0 = g << 4;
  const float4* w34 = (const float4*)w3;    // row = 192 f4
  const float4* h2p4 = (const float4*)h2p;  // row = 64 f4
  const float4* b24 = (const float4*)b2;
  #pragma unroll
  for (int it = 0; it < 6; ++it) {
    int idx = it * 512 + tid, cc = idx & 255, j4 = idx >> 8;
    if (cc < CCEP) wlds4[j4 * 256 + cc] = w34[cc * 192 + kc * 12 + j4];
  }
  if (tid < 72) {
    int r = tid >> 2, cg = tid & 3, tt = t0 - 1 + r;
    float4 s = make_float4(0.f, 0.f, 0.f, 0.f);
    if (tt >= 0 && tt < T_FRAMES) {
      s = b24[kc * 4 + cg];
      #pragma unroll
      for (int p = 0; p < 16; ++p) {
        float4 v = h2p4[((p << 8) + tt) * 64 + kc * 4 + cg];
        s.x += v.x; s.y += v.y; s.z += v.z; s.w += v.w;
      }
      s.x = fmaxf(s.x, 0.f); s.y = fmaxf(s.y, 0.f); s.z = fmaxf(s.z, 0.f); s.w = fmaxf(s.w, 0.f);
    }
    inlds4[tid] = s;
  }
  __syncthreads();
  const int c = tid & 255, fh = tid >> 8;
  if (c < CCEP) {
    float acc[8] = {0.f, 0.f, 0.f, 0.f, 0.f, 0.f, 0.f, 0.f};
    conv_inner(wlds4, inlds4, c, fh, acc);
    const int ob = kc << 8;
    #pragma unroll
    for (int j = 0; j < 8; ++j) ccp[(ob + t0 + fh * 8 + j) * CCEP + c] = acc[j];
  }
}

// ---- K4: fused spectral kernel (correlation theorem, one fwd + one inv FFT) ----
__global__ __launch_bounds__(512) void fftltv_k(const float* __restrict__ ccp, const float* __restrict__ b3,
                                                const float* __restrict__ quef, const float* __restrict__ z,
                                                const float* __restrict__ win, float* __restrict__ outw) {
  __shared__ float2 U[FFT_N];
  int t = blockIdx.x, tid = threadIdx.x;
  for (int i = tid; i < FFT_N; i += 512) {
    unsigned q = br10((unsigned)i);
    float a = 0.f, bv = 0.f;
    if (q >= 401u && q < 623u) {
      int cq = (int)(q - 401u);
      float s = b3[cq];
      #pragma unroll
      for (int p = 0; p < 16; ++p) s += ccp[((p << 8) + t) * CCEP + cq];
      a = s / quef[cq];
    }
    if (q < 512u) {
      int idx = t * HOP + (int)q - 255;
      bv = (idx >= 0 && idx < ZLEN) ? z[idx] : 0.f;
    }
    U[i] = make_float2(a, bv);
  }
  __syncthreads();
  #pragma unroll
  for (int s = 1; s <= 10; ++s) {
    int half = 1 << (s - 1);
    int pos = tid & (half - 1);
    int i1 = ((tid >> (s - 1)) << s) + pos;
    int i2 = i1 + half;
    float ang = (-6.283185307179586f / (float)(1 << s)) * (float)pos;
    float sn, cs; __sincosf(ang, &sn, &cs);
    float2 v2 = U[i2], v1 = U[i1];
    float tr = cs * v2.x - sn * v2.y;
    float ti = cs * v2.y + sn * v2.x;
    U[i1] = make_float2(v1.x + tr, v1.y + ti);
    U[i2] = make_float2(v1.x - tr, v1.y - ti);
    __syncthreads();
  }
  {
    int j = tid;
    int mj = (FFT_N - j) & (FFT_N - 1);
    float2 Uj = U[j], Um = U[mj];
    float2 U5j = make_float2(0.f, 0.f);
    if (tid == 0) U5j = U[512];
    auto pcalc = [](float2 Uj, float2 Um) -> float2 {
      float Ar = 0.5f * (Uj.x + Um.x);
      float Ai = 0.5f * (Uj.y - Um.y);
      float Bx = 0.5f * (Uj.y + Um.y);
      float By = 0.5f * (Um.x - Uj.x);
      float mag = __expf(0.23025850929940457f * Ar);
      float sn, cs; __sincosf(Ai, &sn, &cs);
      float SPx = mag * cs, SPy = mag * sn;
      return make_float2(Bx * SPx + By * SPy, Bx * SPy - By * SPx);
    };
    float2 Pj = pcalc(Uj, Um);
    float2 P5 = (tid == 0) ? pcalc(U5j, U5j) : make_float2(0.f, 0.f);
    __syncthreads();
    U[j] = Pj;
    if (tid == 0) U[512] = P5;
    else U[mj] = make_float2(Pj.x, -Pj.y);
  }
  __syncthreads();
  #pragma unroll
  for (int s = 10; s >= 1; --s) {
    int half = 1 << (s - 1);
    int pos = tid & (half - 1);
    int i1 = ((tid >> (s - 1)) << s) + pos;
    int i2 = i1 + half;
    float ang = (6.283185307179586f / (float)(1 << s)) * (float)pos;
    float sn, cs; __sincosf(ang, &sn, &cs);
    float2 v1 = U[i1], v2 = U[i2];
    U[i1] = make_float2(v1.x + v2.x, v1.y + v2.y);
    float dr = v1.x - v2.x, di = v1.y - v2.y;
    U[i2] = make_float2(cs * dr - sn * di, cs * di + sn * dr);
    __syncthreads();
  }
  const float inv = 1.0f / (float)FFT_N;
  for (int i = tid; i < FFT_N; i += 512) {
    unsigned m = br10((unsigned)i);
    if (m < 512u) {
      int w = 511 - (int)m;
      outw[t * WINL + w] = U[i].x * inv * win[w];
    }
  }
}

// ---- K5: overlap-add (circular roll over t) + 128-tap postfilter ----
__global__ __launch_bounds__(256) void pf_k(const float* __restrict__ outw, const float* __restrict__ pf_w,
                                            const float* __restrict__ pf_b, float* __restrict__ y) {
  __shared__ float sb[256 + PF_KT - 1];
  __shared__ float wpf[PF_KT];
  int n0 = blockIdx.x * 256;
  for (int i = threadIdx.x; i < 256 + PF_KT - 1; i += 256) {
    int m = n0 - 63 + i;
    float v = 0.f;
    if (m >= 0 && m < ZLEN) {
      int t = m >> 8, j = m & 255;
      v = outw[t * WINL + j] + outw[((t - 1) & 255) * WINL + HOP + j];
    }
    sb[i] = v;
  }
  if (threadIdx.x < PF_KT) wpf[threadIdx.x] = pf_w[threadIdx.x];
  __syncthreads();
  float acc = pf_b[0];
  #pragma unroll 8
  for (int j = 0; j < PF_KT; ++j) acc += sb[threadIdx.x + j] * wpf[j];
  y[n0 + threadIdx.x] = acc;
}

extern "C" void kernel_launch(void* const* d_in, const int* in_sizes, int n_in,
                              void* d_out, int out_size, void* d_ws, size_t ws_size,
                              hipStream_t stream) {
  const float* x    = (const float*)d_in[0];
  const float* z    = (const float*)d_in[1];
  const float* w1   = (const float*)d_in[2];
  const float* b1   = (const float*)d_in[3];
  const float* w2   = (const float*)d_in[4];
  const float* b2   = (const float*)d_in[5];
  const float* w3   = (const float*)d_in[6];
  const float* b3   = (const float*)d_in[7];
  const float* pf_w = (const float*)d_in[8];
  const float* pf_b = (const float*)d_in[9];
  const float* quef = (const float*)d_in[10];
  const float* win  = (const float*)d_in[11];
  float* out = (float*)d_out;
  float* ws  = (float*)d_ws;

  // workspace layout (floats)
  float* h1p  = ws;                 // 5*256*256  = 327680
  float* h2p  = h1p + 327680;       // 16*256*256 = 1048576
  float* ccp  = h2p + 1048576;      // 16*256*222 = 909312
  float* outw = ccp + 909312;       // 256*512    = 131072

  conv1_k<<<dim3(5, 16), 512, 0, stream>>>(x, w1, h1p);
  conv2_k<<<dim3(16, 16), 512, 0, stream>>>(h1p, b1, w2, h2p);
  conv3_k<<<dim3(16, 16), 512, 0, stream>>>(h2p, b2, w3, ccp);
  fftltv_k<<<T_FRAMES, 512, 0, stream>>>(ccp, b3, quef, z, win, outw);
  pf_k<<<ZLEN / 256, 256, 0, stream>>>(outw, pf_w, pf_b, out);
}